// Round 6
// baseline (3483.457 us; speedup 1.0000x reference)
//
#include <hip/hip_runtime.h>
#include <math.h>

#define NN 100000
#define FIN 500
#define HIDN 64
#define KF 5
#define DORD 10
#define KPAD 512
#define NKT 8
#define FUSE_GRID 1536
#define RPW_MAX 17

typedef unsigned short ushort_t;
typedef __attribute__((ext_vector_type(8))) short short8v;
typedef __attribute__((ext_vector_type(4))) float f32x4;

struct Tables { float sinc[KF][DORD+1]; float cosc[KF][DORD+1]; };

// bf16 helpers: low/high halves of a packed uint, RNE pack
__device__ inline float bl(unsigned u) { return __uint_as_float(u << 16); }
__device__ inline float bh(unsigned u) { return __uint_as_float(u & 0xffff0000u); }
__device__ inline unsigned short bf16_rne(float x) {
    unsigned u = __float_as_uint(x);
    return (unsigned short)((u + 0x7fffu + ((u >> 16) & 1u)) >> 16);
}
__device__ inline unsigned pack_bf16x2(float a, float b) {
    return (unsigned)bf16_rne(a) | ((unsigned)bf16_rne(b) << 16);
}

// ---- coeff[d] = sum_k alpha[k]*sinc[k][d] + beta[k]*cosc[k][d] ----
__global__ void coeff_kernel(const float* __restrict__ alpha, const float* __restrict__ beta,
                             Tables tb, float* __restrict__ coeff) {
    int d = threadIdx.x;
    if (d <= DORD) {
        float c = 0.f;
        #pragma unroll
        for (int k = 0; k < KF; ++k)
            c += alpha[k] * tb.sinc[k][d] + beta[k] * tb.cosc[k][d];
        coeff[d] = c;
    }
}

// Buckets are 256 nodes wide (power of 2): bucket = v >> 8, offset = v & 255.
#define CHUNK 4096

// ---- pass 0: per-chunk dst-bucket AND src-bucket histograms (no global atomics) ----
__global__ __launch_bounds__(256) void hist_kernel(
    const int* __restrict__ src, const int* __restrict__ dst,
    int* __restrict__ histD, int* __restrict__ histS, int E, int nb) {
    __shared__ int hD[512];
    __shared__ int hS[512];
    for (int i = threadIdx.x; i < 512; i += 256) { hD[i] = 0; hS[i] = 0; }
    __syncthreads();
    int base = blockIdx.x * CHUNK;
    int end = base + CHUNK; if (end > E) end = E;
    for (int e = base + threadIdx.x; e < end; e += 256) {
        int s = src[e], d = dst[e];
        if (s != d) {
            atomicAdd(&hD[d >> 8], 1);
            atomicAdd(&hS[s >> 8], 1);
        }
    }
    __syncthreads();
    size_t ro = (size_t)blockIdx.x * 512;
    for (int i = threadIdx.x; i < nb; i += 256) {
        histD[ro + i] = hD[i];
        histS[ro + i] = hS[i];
    }
}

// ---- pass 0.5a: per-bucket exclusive scan over chunks (in place) + bucket totals ----
__global__ __launch_bounds__(512) void scanA_kernel(
    int* __restrict__ histD, int* __restrict__ histS,
    int* __restrict__ totD, int* __restrict__ totS, int nchunk, int nb) {
    __shared__ int tmp[512];
    int x = blockIdx.x;
    int* hist; int* tot; int b;
    if (x < nb) { hist = histD; tot = totD; b = x; }
    else        { hist = histS; tot = totS; b = x - nb; }
    int t = threadIdx.x;
    int carry = 0;
    for (int c0 = 0; c0 < nchunk; c0 += 512) {
        int c = c0 + t;
        tmp[t] = (c < nchunk) ? hist[(size_t)c * 512 + b] : 0;
        __syncthreads();
        for (int off = 1; off < 512; off <<= 1) {
            int add = (t >= off) ? tmp[t - off] : 0;
            __syncthreads();
            tmp[t] += add;
            __syncthreads();
        }
        if (c < nchunk) hist[(size_t)c * 512 + b] = carry + ((t > 0) ? tmp[t - 1] : 0);
        carry += tmp[511];
        __syncthreads();
    }
    if (t == 0) tot[b] = carry;
}

// ---- pass 0.5b: exclusive scan over bucket totals -> absolute bucket bases ----
__global__ __launch_bounds__(512) void scanB_kernel(
    const int* __restrict__ totD, const int* __restrict__ totS,
    int* __restrict__ offD, int* __restrict__ offS, int nb) {
    __shared__ int tmp[512];
    int t = threadIdx.x;
    tmp[t] = (t < nb) ? totD[t] : 0;
    __syncthreads();
    for (int off = 1; off < 512; off <<= 1) {
        int add = (t >= off) ? tmp[t - off] : 0;
        __syncthreads();
        tmp[t] += add;
        __syncthreads();
    }
    if (t < nb) offD[t] = (t > 0) ? tmp[t - 1] : 0;
    if (t == nb - 1) offD[nb] = tmp[t];
    __syncthreads();
    tmp[t] = (t < nb) ? totS[t] : 0;
    __syncthreads();
    for (int off = 1; off < 512; off <<= 1) {
        int add = (t >= off) ? tmp[t - off] : 0;
        __syncthreads();
        tmp[t] += add;
        __syncthreads();
    }
    if (t < nb) offS[t] = (t > 0) ? tmp[t - 1] : 0;
    if (t == nb - 1) offS[nb] = tmp[t];
}

// ---- pass 1: scatter with precomputed deterministic cursors (LDS atomics only) ----
__global__ __launch_bounds__(256) void scatter_kernel(
    const int* __restrict__ src, const int* __restrict__ dst,
    const int* __restrict__ histD, const int* __restrict__ histS,
    const int* __restrict__ offD, const int* __restrict__ offS,
    unsigned* __restrict__ binned, unsigned char* __restrict__ srcbin, int E, int nb) {
    __shared__ int cD[512];
    __shared__ int cS[512];
    size_t ro = (size_t)blockIdx.x * 512;
    for (int i = threadIdx.x; i < nb; i += 256) {
        cD[i] = offD[i] + histD[ro + i];
        cS[i] = offS[i] + histS[ro + i];
    }
    __syncthreads();
    int base = blockIdx.x * CHUNK;
    int end = base + CHUNK; if (end > E) end = E;
    for (int e = base + threadIdx.x; e < end; e += 256) {
        int s = src[e], d = dst[e];
        if (s != d) {
            int pD = atomicAdd(&cD[d >> 8], 1);
            binned[pD] = (unsigned)s | ((unsigned)(d & 255) << 24);
            int pS = atomicAdd(&cS[s >> 8], 1);
            srcbin[pS] = (unsigned char)(s & 255);
        }
    }
}

// ---- pass 2a: one block owns one bucket: local indeg, scan, row_ptr, col ----
__global__ __launch_bounds__(256) void bucket_csr_kernel(
    const unsigned* __restrict__ binned, const int* __restrict__ offD,
    int* __restrict__ row_ptr, int* __restrict__ col, int n, int nb) {
    int b = blockIdx.x;
    int e0 = offD[b], e1 = offD[b + 1];
    int d0 = b << 8;
    int dn = n - d0; if (dn > 256) dn = 256;
    __shared__ int ind[256];
    __shared__ int cur[256];
    int t = threadIdx.x;
    ind[t] = 0;
    __syncthreads();
    for (int e = e0 + t; e < e1; e += 256) {
        unsigned p = binned[e];
        atomicAdd(&ind[p >> 24], 1);
    }
    __syncthreads();
    for (int off = 1; off < 256; off <<= 1) {
        int add = (t >= off) ? ind[t - off] : 0;
        __syncthreads();
        ind[t] += add;
        __syncthreads();
    }
    if (t < dn) {
        int excl = (t > 0) ? ind[t - 1] : 0;
        row_ptr[d0 + t] = e0 + excl;
        cur[t] = e0 + excl;
    }
    if (b == 0 && t == 0) row_ptr[n] = offD[nb];
    __syncthreads();
    for (int e = e0 + t; e < e1; e += 256) {
        unsigned p = binned[e];
        int pos = atomicAdd(&cur[p >> 24], 1);
        col[pos] = (int)(p & 0xFFFFFFu);
    }
}

// ---- pass 2b: out-degree per node from src-binned bytes -> dinv ----
__global__ __launch_bounds__(256) void dinv_count_kernel(
    const unsigned char* __restrict__ srcbin, const int* __restrict__ offS,
    float* __restrict__ dinv, int n, int nb) {
    __shared__ int ind[256];
    int b = blockIdx.x;
    int t = threadIdx.x;
    ind[t] = 0;
    __syncthreads();
    int e0 = offS[b], e1 = offS[b + 1];
    for (int e = e0 + t; e < e1; e += 256)
        atomicAdd(&ind[srcbin[e]], 1);
    __syncthreads();
    int i = (b << 8) + t;
    if (i < n) {
        int c = ind[t];
        dinv[i] = (c > 0) ? (1.0f / sqrtf((float)c)) : 0.f;
    }
}

// ---- W1 -> bf16, transposed, K-padded: Wt[c][k] = bf16(W1[k][c]), k<500 else 0 ----
__global__ __launch_bounds__(256) void wprep_kernel(
    const float* __restrict__ W1, ushort_t* __restrict__ Wt) {
    int tid = blockIdx.x * 256 + threadIdx.x;       // 64*512 = 32768 elems
    if (tid >= 64 * KPAD) return;
    int kk = tid & (KPAD - 1);
    int c = tid >> 9;
    float v = (kk < FIN) ? W1[(size_t)kk * 64 + c] : 0.f;
    Wt[(size_t)c * KPAD + kk] = bf16_rne(v);
}

// ---- GEMM1 via MFMA bf16: H = relu(A[n,500] @ W[500,64] + b) ----
__global__ __launch_bounds__(256) void gemm1_mfma_kernel(
    const float* __restrict__ A, const ushort_t* __restrict__ Wt,
    const float* __restrict__ bias, float* __restrict__ H, int n) {
    __shared__ ushort_t sA[128][72];
    __shared__ ushort_t sB[64][72];
    int t = threadIdx.x;
    int w = t >> 6;            // wave 0..3 -> rows [w*32, w*32+32)
    int lane = t & 63;
    int lr = lane & 15;        // fragment row/col index
    int lg = lane >> 4;        // k-group (0..3)
    int rowBase = blockIdx.x * 128;

    f32x4 acc[2][4];
    #pragma unroll
    for (int r = 0; r < 2; ++r)
        #pragma unroll
        for (int c = 0; c < 4; ++c)
            acc[r][c] = (f32x4){0.f, 0.f, 0.f, 0.f};

    for (int kt = 0; kt < NKT; ++kt) {
        #pragma unroll
        for (int l = 0; l < 8; ++l) {
            int idx = t + l * 256;
            int r = idx >> 4;
            int kc = (idx & 15) * 4;
            int gr = rowBase + r;
            int gk = kt * 64 + kc;
            float4 v = make_float4(0.f, 0.f, 0.f, 0.f);
            if (gr < n) {
                if (gk + 3 < FIN) {
                    v = *(const float4*)(A + (size_t)gr * FIN + gk);
                } else {
                    float* vp = (float*)&v;
                    #pragma unroll
                    for (int j = 0; j < 4; ++j)
                        if (gk + j < FIN) vp[j] = A[(size_t)gr * FIN + gk + j];
                }
            }
            uint2 p;
            p.x = pack_bf16x2(v.x, v.y);
            p.y = pack_bf16x2(v.z, v.w);
            *(uint2*)&sA[r][kc] = p;
        }
        #pragma unroll
        for (int l = 0; l < 2; ++l) {
            int idx = t + l * 256;
            int c = idx >> 3;
            int kc = (idx & 7) * 8;
            uint4 v = *(const uint4*)(Wt + (size_t)c * KPAD + kt * 64 + kc);
            *(uint4*)&sB[c][kc] = v;
        }
        __syncthreads();

        short8v af[2][2], bfr[4][2];
        #pragma unroll
        for (int r = 0; r < 2; ++r)
            #pragma unroll
            for (int h = 0; h < 2; ++h)
                af[r][h] = *(const short8v*)&sA[w * 32 + r * 16 + lr][h * 32 + lg * 8];
        #pragma unroll
        for (int c = 0; c < 4; ++c)
            #pragma unroll
            for (int h = 0; h < 2; ++h)
                bfr[c][h] = *(const short8v*)&sB[c * 16 + lr][h * 32 + lg * 8];
        #pragma unroll
        for (int r = 0; r < 2; ++r)
            #pragma unroll
            for (int c = 0; c < 4; ++c)
                #pragma unroll
                for (int h = 0; h < 2; ++h)
                    acc[r][c] = __builtin_amdgcn_mfma_f32_16x16x32_bf16(
                        af[r][h], bfr[c][h], acc[r][c], 0, 0, 0);
        __syncthreads();
    }

    float bcol[4];
    #pragma unroll
    for (int c = 0; c < 4; ++c) bcol[c] = bias[c * 16 + lr];
    #pragma unroll
    for (int r = 0; r < 2; ++r) {
        #pragma unroll
        for (int c = 0; c < 4; ++c) {
            #pragma unroll
            for (int i = 0; i < 4; ++i) {
                int row = rowBase + w * 32 + r * 16 + lg * 4 + i;
                if (row < n)
                    H[(size_t)row * 64 + c * 16 + lr] = fmaxf(acc[r][c][i] + bcol[c], 0.f);
            }
        }
    }
}

// ---- GEMM2: X = H @ W2 + b2 ; out = (1+coeff[0])*X ; ty0 = bf16(dinv ⊙ X) ----
__global__ __launch_bounds__(256) void gemm2_kernel(
    const float* __restrict__ H, const float* __restrict__ W2,
    const float* __restrict__ b2, const float* __restrict__ coeff,
    const float* __restrict__ dinv, ushort_t* __restrict__ ty0,
    float* __restrict__ out, int n) {
    __shared__ float sW[64 * 64];
    __shared__ float sb[64];
    int t = threadIdx.x;
    for (int i = t; i < 4096; i += 256) sW[i] = W2[i];
    if (t < 64) sb[t] = b2[t];
    __syncthreads();
    float c0p1 = 1.f + coeff[0];
    int lane = t & 63;
    int wid = t >> 6;
    int r0 = blockIdx.x * 128;
    int rend = r0 + 128; if (rend > n) rend = n;
    for (int r = r0 + wid; r < rend; r += 4) {
        float hv = H[(size_t)r * 64 + lane];
        float dr = dinv[r];
        float acc = sb[lane];
        #pragma unroll
        for (int k = 0; k < 64; ++k)
            acc = fmaf(__shfl(hv, k, 64), sW[k * 64 + lane], acc);
        ty0[(size_t)r * 64 + lane] = bf16_rne(dr * acc);
        out[(size_t)r * 64 + lane] = c0p1 * acc;
    }
}

// ---- device-scope grid barrier (co-residency guaranteed by launch_bounds+grid) ----
__device__ __forceinline__ void grid_bar(int* cnt, int* flag, int nblk) {
    __syncthreads();
    if (threadIdx.x == 0) {
        __threadfence();   // release: write back this XCD's L2
        int old = __hip_atomic_fetch_add(cnt, 1, __ATOMIC_ACQ_REL, __HIP_MEMORY_SCOPE_AGENT);
        if (old == nblk - 1) {
            __hip_atomic_store(flag, 1, __ATOMIC_RELEASE, __HIP_MEMORY_SCOPE_AGENT);
        } else {
            while (__hip_atomic_load(flag, __ATOMIC_RELAXED, __HIP_MEMORY_SCOPE_AGENT) == 0)
                __builtin_amdgcn_s_sleep(8);
        }
        __threadfence();   // acquire: invalidate stale L2/L1 lines
    }
    __syncthreads();
}

// ---- fused diffusion: all DORD hops + out accumulation (LDS) + log-softmax ----
// Wave owns rpw contiguous rows for the whole kernel. Per hop per row:
// gather (8 edge-slots x 8 feat-lanes, uint4), butterfly ALLreduce -> every lane
// holds its feat-block sums; lane L accumulates feat (L&7)*8+(L>>3) into LDS.
__global__ __launch_bounds__(256, 6) void diffuse_kernel(
    const int* __restrict__ row_ptr, const int* __restrict__ col,
    const float* __restrict__ dinv, const float* __restrict__ coeff,
    ushort_t* TyA, ushort_t* TyB,
    float* out, int* bars, int n) {
    __shared__ float oacc[4][RPW_MAX][64];
    int t = threadIdx.x;
    int w = t >> 6, lane = t & 63;
    int sub = lane >> 3;       // 0..7: edge slot / selector
    int fl = lane & 7;         // feature block
    int nblk = gridDim.x;
    int nw = nblk * 4;
    int rpw = (n + nw - 1) / nw;
    if (rpw > RPW_MAX) rpw = RPW_MAX;
    int gid = blockIdx.x * 4 + w;
    int r0 = gid * rpw;
    int r1 = r0 + rpw; if (r1 > n) r1 = n;
    int fmap = fl * 8 + sub;   // this lane's feature index

    for (int r = r0; r < r1; ++r)
        oacc[w][r - r0][lane] = out[(size_t)r * 64 + fmap];

    for (int d = 1; d <= DORD; ++d) {
        const ushort_t* tin = ((d - 1) & 1) ? TyB : TyA;
        ushort_t* tout = (d & 1) ? TyB : TyA;
        float cd = coeff[d];
        for (int r = r0; r < r1; ++r) {
            int e0 = row_ptr[r], e1 = row_ptr[r + 1];
            float a0 = 0.f, a1 = 0.f, a2 = 0.f, a3 = 0.f;
            float a4 = 0.f, a5 = 0.f, a6 = 0.f, a7 = 0.f;
            int e = e0 + sub;
            for (; e + 8 < e1; e += 16) {
                int s0 = col[e], s1 = col[e + 8];
                uint4 p0 = *(const uint4*)(tin + (size_t)s0 * 64 + fl * 8);
                uint4 p1 = *(const uint4*)(tin + (size_t)s1 * 64 + fl * 8);
                a0 += bl(p0.x) + bl(p1.x); a1 += bh(p0.x) + bh(p1.x);
                a2 += bl(p0.y) + bl(p1.y); a3 += bh(p0.y) + bh(p1.y);
                a4 += bl(p0.z) + bl(p1.z); a5 += bh(p0.z) + bh(p1.z);
                a6 += bl(p0.w) + bl(p1.w); a7 += bh(p0.w) + bh(p1.w);
            }
            if (e < e1) {
                int s = col[e];
                uint4 p = *(const uint4*)(tin + (size_t)s * 64 + fl * 8);
                a0 += bl(p.x); a1 += bh(p.x); a2 += bl(p.y); a3 += bh(p.y);
                a4 += bl(p.z); a5 += bh(p.z); a6 += bl(p.w); a7 += bh(p.w);
            }
            #pragma unroll
            for (int off = 8; off <= 32; off <<= 1) {   // butterfly: ALL lanes get sums
                a0 += __shfl_xor(a0, off, 64); a1 += __shfl_xor(a1, off, 64);
                a2 += __shfl_xor(a2, off, 64); a3 += __shfl_xor(a3, off, 64);
                a4 += __shfl_xor(a4, off, 64); a5 += __shfl_xor(a5, off, 64);
                a6 += __shfl_xor(a6, off, 64); a7 += __shfl_xor(a7, off, 64);
            }
            float dr = dinv[r];
            float t0 = -dr * a0, t1 = -dr * a1, t2 = -dr * a2, t3 = -dr * a3;
            float t4 = -dr * a4, t5 = -dr * a5, t6 = -dr * a6, t7 = -dr * a7;
            if (d < DORD && sub == 0) {   // lanes 0..7 write the bf16 state row
                uint4 ty;
                ty.x = pack_bf16x2(dr * t0, dr * t1);
                ty.y = pack_bf16x2(dr * t2, dr * t3);
                ty.z = pack_bf16x2(dr * t4, dr * t5);
                ty.w = pack_bf16x2(dr * t6, dr * t7);
                *(uint4*)(tout + (size_t)r * 64 + fl * 8) = ty;
            }
            float tj = (sub < 4) ? ((sub < 2) ? (sub == 0 ? t0 : t1) : (sub == 2 ? t2 : t3))
                                 : ((sub < 6) ? (sub == 4 ? t4 : t5) : (sub == 6 ? t6 : t7));
            oacc[w][r - r0][lane] += cd * tj;
        }
        if (d < DORD)
            grid_bar(&bars[2 * d], &bars[2 * d + 1], nblk);
    }

    for (int r = r0; r < r1; ++r) {
        float v = oacc[w][r - r0][lane];
        float m = v;
        #pragma unroll
        for (int off = 1; off < 64; off <<= 1) m = fmaxf(m, __shfl_xor(m, off, 64));
        float s = expf(v - m);
        #pragma unroll
        for (int off = 1; off < 64; off <<= 1) s += __shfl_xor(s, off, 64);
        float lse = m + logf(s);
        out[(size_t)r * 64 + fmap] = v - lse;
    }
}

extern "C" void kernel_launch(void* const* d_in, const int* in_sizes, int n_in,
                              void* d_out, int out_size, void* d_ws, size_t ws_size,
                              hipStream_t stream) {
    const float* feature = (const float*)d_in[0];
    const int*   edges   = (const int*)d_in[1];
    const float* W1      = (const float*)d_in[2];
    const float* b1      = (const float*)d_in[3];
    const float* W2      = (const float*)d_in[4];
    const float* b2      = (const float*)d_in[5];
    const float* alpha   = (const float*)d_in[6];
    const float* beta    = (const float*)d_in[7];
    float* out = (float*)d_out;

    const int n = in_sizes[0] / FIN;      // 100000
    const int E = in_sizes[1] / 2;        // 3200000
    const int* src = edges;
    const int* dst = edges + E;

    const int nb = (n + 255) >> 8;        // 391 buckets of 256 nodes
    const int nchunk = (E + CHUNK - 1) / CHUNK;
    const size_t n64 = (size_t)n * 64;

    // ---- workspace layout (256B aligned) ----
    char* ws = (char*)d_ws;
    size_t off = 0;
    auto alloc = [&](size_t bytes) { size_t o = off; off = (off + bytes + 255) & ~(size_t)255; return o; };
    float*         coeff   = (float*)        (ws + alloc(64 * 4));
    int*           bars    = (int*)          (ws + alloc(64 * 4));
    float*         dinv    = (float*)        (ws + alloc((size_t)n * 4));
    int*           row_ptr = (int*)          (ws + alloc(((size_t)n + 1) * 4));
    int*           offD    = (int*)          (ws + alloc(513 * 4));
    int*           offS    = (int*)          (ws + alloc(513 * 4));
    int*           totD    = (int*)          (ws + alloc(512 * 4));
    int*           totS    = (int*)          (ws + alloc(512 * 4));
    ushort_t*      Wt      = (ushort_t*)     (ws + alloc((size_t)64 * KPAD * 2));
    int*           histD   = (int*)          (ws + alloc((size_t)nchunk * 512 * 4));
    int*           histS   = (int*)          (ws + alloc((size_t)nchunk * 512 * 4));
    int*           col     = (int*)          (ws + alloc((size_t)E * 4));
    unsigned*      binned  = (unsigned*)     (ws + alloc((size_t)E * 4));
    unsigned char* srcbin  = (unsigned char*)(ws + alloc((size_t)E));
    float*         H       = (float*)        (ws + alloc(n64 * 4));
    ushort_t*      TyA     = (ushort_t*)     (ws + alloc(n64 * 2));
    ushort_t*      TyB     = (ushort_t*)     (ws + alloc(n64 * 2));

    // ---- host-side Taylor tables (deterministic, recomputed every call) ----
    Tables tb;
    for (int k = 0; k < KF; ++k) {
        double x = M_PI * (double)(k + 1);   // OMEGA = 1
        double p = 1.0, f = 1.0;
        for (int o = 0; o <= DORD; ++o) {
            if (o > 0) { p *= x; f *= (double)o; }
            double v = p / f;
            tb.cosc[k][o] = (o % 2 == 0) ? (float)((((o / 2) % 2 == 0) ? 1.0 : -1.0) * v) : 0.f;
            tb.sinc[k][o] = (o % 2 == 1) ? (float)(((((o - 1) / 2) % 2 == 0) ? 1.0 : -1.0) * v) : 0.f;
        }
    }

    hipMemsetAsync(bars, 0, 64 * 4, stream);
    coeff_kernel<<<1, 64, 0, stream>>>(alpha, beta, tb, coeff);
    wprep_kernel<<<(64 * KPAD + 255) / 256, 256, 0, stream>>>(W1, Wt);

    hist_kernel<<<nchunk, 256, 0, stream>>>(src, dst, histD, histS, E, nb);
    scanA_kernel<<<2 * nb, 512, 0, stream>>>(histD, histS, totD, totS, nchunk, nb);
    scanB_kernel<<<1, 512, 0, stream>>>(totD, totS, offD, offS, nb);
    scatter_kernel<<<nchunk, 256, 0, stream>>>(src, dst, histD, histS, offD, offS,
                                               binned, srcbin, E, nb);
    bucket_csr_kernel<<<nb, 256, 0, stream>>>(binned, offD, row_ptr, col, n, nb);
    dinv_count_kernel<<<nb, 256, 0, stream>>>(srcbin, offS, dinv, n, nb);

    gemm1_mfma_kernel<<<(n + 127) / 128, 256, 0, stream>>>(feature, Wt, b1, H, n);
    gemm2_kernel<<<(n + 127) / 128, 256, 0, stream>>>(H, W2, b2, coeff, dinv, TyA, out, n);

    diffuse_kernel<<<FUSE_GRID, 256, 0, stream>>>(row_ptr, col, dinv, coeff,
                                                  TyA, TyB, out, bars, n);
}

// Round 7
// 1096.700 us; speedup vs baseline: 3.1763x; 3.1763x over previous
//
#include <hip/hip_runtime.h>
#include <math.h>

#define NN 100000
#define FIN 500
#define HIDN 64
#define KF 5
#define DORD 10
#define KPAD 512
#define NKT 8

typedef unsigned short ushort_t;
typedef __attribute__((ext_vector_type(8))) short short8v;
typedef __attribute__((ext_vector_type(4))) float f32x4;

struct Tables { float sinc[KF][DORD+1]; float cosc[KF][DORD+1]; };

// bf16 helpers: low/high halves of a packed uint, RNE pack
__device__ inline float bl(unsigned u) { return __uint_as_float(u << 16); }
__device__ inline float bh(unsigned u) { return __uint_as_float(u & 0xffff0000u); }
__device__ inline unsigned short bf16_rne(float x) {
    unsigned u = __float_as_uint(x);
    return (unsigned short)((u + 0x7fffu + ((u >> 16) & 1u)) >> 16);
}
__device__ inline unsigned pack_bf16x2(float a, float b) {
    return (unsigned)bf16_rne(a) | ((unsigned)bf16_rne(b) << 16);
}

// ---- coeff[d] = sum_k alpha[k]*sinc[k][d] + beta[k]*cosc[k][d] ----
__global__ void coeff_kernel(const float* __restrict__ alpha, const float* __restrict__ beta,
                             Tables tb, float* __restrict__ coeff) {
    int d = threadIdx.x;
    if (d <= DORD) {
        float c = 0.f;
        #pragma unroll
        for (int k = 0; k < KF; ++k)
            c += alpha[k] * tb.sinc[k][d] + beta[k] * tb.cosc[k][d];
        coeff[d] = c;
    }
}

// Buckets are 256 nodes wide (power of 2): bucket = v >> 8, offset = v & 255.
#define CHUNK 4096

// ---- pass 0: per-chunk dst-bucket AND src-bucket histograms (no global atomics) ----
__global__ __launch_bounds__(256) void hist_kernel(
    const int* __restrict__ src, const int* __restrict__ dst,
    int* __restrict__ histD, int* __restrict__ histS, int E, int nb) {
    __shared__ int hD[512];
    __shared__ int hS[512];
    for (int i = threadIdx.x; i < 512; i += 256) { hD[i] = 0; hS[i] = 0; }
    __syncthreads();
    int base = blockIdx.x * CHUNK;
    int end = base + CHUNK; if (end > E) end = E;
    for (int e = base + threadIdx.x; e < end; e += 256) {
        int s = src[e], d = dst[e];
        if (s != d) {
            atomicAdd(&hD[d >> 8], 1);
            atomicAdd(&hS[s >> 8], 1);
        }
    }
    __syncthreads();
    size_t ro = (size_t)blockIdx.x * 512;
    for (int i = threadIdx.x; i < nb; i += 256) {
        histD[ro + i] = hD[i];
        histS[ro + i] = hS[i];
    }
}

// ---- pass 0.5a: per-bucket exclusive scan over chunks (in place) + bucket totals ----
__global__ __launch_bounds__(512) void scanA_kernel(
    int* __restrict__ histD, int* __restrict__ histS,
    int* __restrict__ totD, int* __restrict__ totS, int nchunk, int nb) {
    __shared__ int tmp[512];
    int x = blockIdx.x;
    int* hist; int* tot; int b;
    if (x < nb) { hist = histD; tot = totD; b = x; }
    else        { hist = histS; tot = totS; b = x - nb; }
    int t = threadIdx.x;
    int carry = 0;
    for (int c0 = 0; c0 < nchunk; c0 += 512) {
        int c = c0 + t;
        tmp[t] = (c < nchunk) ? hist[(size_t)c * 512 + b] : 0;
        __syncthreads();
        for (int off = 1; off < 512; off <<= 1) {
            int add = (t >= off) ? tmp[t - off] : 0;
            __syncthreads();
            tmp[t] += add;
            __syncthreads();
        }
        if (c < nchunk) hist[(size_t)c * 512 + b] = carry + ((t > 0) ? tmp[t - 1] : 0);
        carry += tmp[511];
        __syncthreads();
    }
    if (t == 0) tot[b] = carry;
}

// ---- pass 0.5b: exclusive scan over bucket totals -> absolute bucket bases ----
__global__ __launch_bounds__(512) void scanB_kernel(
    const int* __restrict__ totD, const int* __restrict__ totS,
    int* __restrict__ offD, int* __restrict__ offS, int nb) {
    __shared__ int tmp[512];
    int t = threadIdx.x;
    tmp[t] = (t < nb) ? totD[t] : 0;
    __syncthreads();
    for (int off = 1; off < 512; off <<= 1) {
        int add = (t >= off) ? tmp[t - off] : 0;
        __syncthreads();
        tmp[t] += add;
        __syncthreads();
    }
    if (t < nb) offD[t] = (t > 0) ? tmp[t - 1] : 0;
    if (t == nb - 1) offD[nb] = tmp[t];
    __syncthreads();
    tmp[t] = (t < nb) ? totS[t] : 0;
    __syncthreads();
    for (int off = 1; off < 512; off <<= 1) {
        int add = (t >= off) ? tmp[t - off] : 0;
        __syncthreads();
        tmp[t] += add;
        __syncthreads();
    }
    if (t < nb) offS[t] = (t > 0) ? tmp[t - 1] : 0;
    if (t == nb - 1) offS[nb] = tmp[t];
}

// ---- pass 1: scatter with precomputed deterministic cursors (LDS atomics only) ----
__global__ __launch_bounds__(256) void scatter_kernel(
    const int* __restrict__ src, const int* __restrict__ dst,
    const int* __restrict__ histD, const int* __restrict__ histS,
    const int* __restrict__ offD, const int* __restrict__ offS,
    unsigned* __restrict__ binned, unsigned char* __restrict__ srcbin, int E, int nb) {
    __shared__ int cD[512];
    __shared__ int cS[512];
    size_t ro = (size_t)blockIdx.x * 512;
    for (int i = threadIdx.x; i < nb; i += 256) {
        cD[i] = offD[i] + histD[ro + i];
        cS[i] = offS[i] + histS[ro + i];
    }
    __syncthreads();
    int base = blockIdx.x * CHUNK;
    int end = base + CHUNK; if (end > E) end = E;
    for (int e = base + threadIdx.x; e < end; e += 256) {
        int s = src[e], d = dst[e];
        if (s != d) {
            int pD = atomicAdd(&cD[d >> 8], 1);
            binned[pD] = (unsigned)s | ((unsigned)(d & 255) << 24);
            int pS = atomicAdd(&cS[s >> 8], 1);
            srcbin[pS] = (unsigned char)(s & 255);
        }
    }
}

// ---- pass 2a: one block owns one bucket: local indeg, scan, row_ptr, col ----
__global__ __launch_bounds__(256) void bucket_csr_kernel(
    const unsigned* __restrict__ binned, const int* __restrict__ offD,
    int* __restrict__ row_ptr, int* __restrict__ col, int n, int nb) {
    int b = blockIdx.x;
    int e0 = offD[b], e1 = offD[b + 1];
    int d0 = b << 8;
    int dn = n - d0; if (dn > 256) dn = 256;
    __shared__ int ind[256];
    __shared__ int cur[256];
    int t = threadIdx.x;
    ind[t] = 0;
    __syncthreads();
    for (int e = e0 + t; e < e1; e += 256) {
        unsigned p = binned[e];
        atomicAdd(&ind[p >> 24], 1);
    }
    __syncthreads();
    for (int off = 1; off < 256; off <<= 1) {
        int add = (t >= off) ? ind[t - off] : 0;
        __syncthreads();
        ind[t] += add;
        __syncthreads();
    }
    if (t < dn) {
        int excl = (t > 0) ? ind[t - 1] : 0;
        row_ptr[d0 + t] = e0 + excl;
        cur[t] = e0 + excl;
    }
    if (b == 0 && t == 0) row_ptr[n] = offD[nb];
    __syncthreads();
    for (int e = e0 + t; e < e1; e += 256) {
        unsigned p = binned[e];
        int pos = atomicAdd(&cur[p >> 24], 1);
        col[pos] = (int)(p & 0xFFFFFFu);
    }
}

// ---- pass 2b: out-degree per node from src-binned bytes -> dinv ----
__global__ __launch_bounds__(256) void dinv_count_kernel(
    const unsigned char* __restrict__ srcbin, const int* __restrict__ offS,
    float* __restrict__ dinv, int n, int nb) {
    __shared__ int ind[256];
    int b = blockIdx.x;
    int t = threadIdx.x;
    ind[t] = 0;
    __syncthreads();
    int e0 = offS[b], e1 = offS[b + 1];
    for (int e = e0 + t; e < e1; e += 256)
        atomicAdd(&ind[srcbin[e]], 1);
    __syncthreads();
    int i = (b << 8) + t;
    if (i < n) {
        int c = ind[t];
        dinv[i] = (c > 0) ? (1.0f / sqrtf((float)c)) : 0.f;
    }
}

// ---- W1 -> bf16 W1^T K-padded [64][512]; W2 -> bf16 W2^T [64][64] ----
__global__ __launch_bounds__(256) void wprep_kernel(
    const float* __restrict__ W1, const float* __restrict__ W2,
    ushort_t* __restrict__ Wt, ushort_t* __restrict__ W2t) {
    int tid = blockIdx.x * 256 + threadIdx.x;
    if (tid < 64 * KPAD) {
        int kk = tid & (KPAD - 1);
        int c = tid >> 9;
        float v = (kk < FIN) ? W1[(size_t)kk * 64 + c] : 0.f;
        Wt[(size_t)c * KPAD + kk] = bf16_rne(v);
    } else if (tid < 64 * KPAD + 64 * 64) {
        int j = tid - 64 * KPAD;
        int kk = j & 63;
        int c = j >> 6;
        W2t[(size_t)c * 64 + kk] = bf16_rne(W2[(size_t)kk * 64 + c]);
    }
}

// ---- fused GEMM via MFMA bf16:
//   H = relu(A @ W1 + b1); X = H @ W2 + b2;
//   out = (1+coeff[0])*X ; ty0 = bf16(dinv * X)
__global__ __launch_bounds__(256) void gemm12_kernel(
    const float* __restrict__ A, const ushort_t* __restrict__ Wt,
    const ushort_t* __restrict__ W2t,
    const float* __restrict__ b1, const float* __restrict__ b2,
    const float* __restrict__ coeff, const float* __restrict__ dinv,
    ushort_t* __restrict__ ty0, float* __restrict__ out, int n) {
    __shared__ ushort_t sA[128][72];
    __shared__ ushort_t sB[64][72];
    __shared__ ushort_t sB2[64][72];
    int t = threadIdx.x;
    int w = t >> 6;            // wave 0..3 -> rows [w*32, w*32+32)
    int lane = t & 63;
    int lr = lane & 15;        // fragment row/col index
    int lg = lane >> 4;        // k-group (0..3)
    int rowBase = blockIdx.x * 128;

    // stage W2^T once (static)
    #pragma unroll
    for (int l = 0; l < 2; ++l) {
        int idx = t + l * 256;             // 512 chunks of 8 bf16
        int c = idx >> 3, kc = (idx & 7) * 8;
        uint4 v = *(const uint4*)(W2t + (size_t)c * 64 + kc);
        *(uint4*)&sB2[c][kc] = v;
    }

    f32x4 acc[2][4];
    #pragma unroll
    for (int r = 0; r < 2; ++r)
        #pragma unroll
        for (int c = 0; c < 4; ++c)
            acc[r][c] = (f32x4){0.f, 0.f, 0.f, 0.f};

    for (int kt = 0; kt < NKT; ++kt) {
        #pragma unroll
        for (int l = 0; l < 8; ++l) {
            int idx = t + l * 256;
            int r = idx >> 4;
            int kc = (idx & 15) * 4;
            int gr = rowBase + r;
            int gk = kt * 64 + kc;
            float4 v = make_float4(0.f, 0.f, 0.f, 0.f);
            if (gr < n) {
                if (gk + 3 < FIN) {
                    v = *(const float4*)(A + (size_t)gr * FIN + gk);
                } else {
                    float* vp = (float*)&v;
                    #pragma unroll
                    for (int j = 0; j < 4; ++j)
                        if (gk + j < FIN) vp[j] = A[(size_t)gr * FIN + gk + j];
                }
            }
            uint2 p;
            p.x = pack_bf16x2(v.x, v.y);
            p.y = pack_bf16x2(v.z, v.w);
            *(uint2*)&sA[r][kc] = p;
        }
        #pragma unroll
        for (int l = 0; l < 2; ++l) {
            int idx = t + l * 256;
            int c = idx >> 3;
            int kc = (idx & 7) * 8;
            uint4 v = *(const uint4*)(Wt + (size_t)c * KPAD + kt * 64 + kc);
            *(uint4*)&sB[c][kc] = v;
        }
        __syncthreads();

        short8v af[2][2], bfr[4][2];
        #pragma unroll
        for (int r = 0; r < 2; ++r)
            #pragma unroll
            for (int h = 0; h < 2; ++h)
                af[r][h] = *(const short8v*)&sA[w * 32 + r * 16 + lr][h * 32 + lg * 8];
        #pragma unroll
        for (int c = 0; c < 4; ++c)
            #pragma unroll
            for (int h = 0; h < 2; ++h)
                bfr[c][h] = *(const short8v*)&sB[c * 16 + lr][h * 32 + lg * 8];
        #pragma unroll
        for (int r = 0; r < 2; ++r)
            #pragma unroll
            for (int c = 0; c < 4; ++c)
                #pragma unroll
                for (int h = 0; h < 2; ++h)
                    acc[r][c] = __builtin_amdgcn_mfma_f32_16x16x32_bf16(
                        af[r][h], bfr[c][h], acc[r][c], 0, 0, 0);
        __syncthreads();
    }

    // H-tile (relu + b1) -> bf16 into sA (D layout: col=lr, row=lg*4+i per 16x16)
    float bcol1[4];
    #pragma unroll
    for (int c = 0; c < 4; ++c) bcol1[c] = b1[c * 16 + lr];
    #pragma unroll
    for (int r = 0; r < 2; ++r)
        #pragma unroll
        for (int c = 0; c < 4; ++c)
            #pragma unroll
            for (int i = 0; i < 4; ++i)
                sA[w * 32 + r * 16 + lg * 4 + i][c * 16 + lr] =
                    bf16_rne(fmaxf(acc[r][c][i] + bcol1[c], 0.f));
    __syncthreads();

    // stage 2: X = H @ W2 (K=64)
    short8v af2[2][2], bf2[4][2];
    #pragma unroll
    for (int r = 0; r < 2; ++r)
        #pragma unroll
        for (int h = 0; h < 2; ++h)
            af2[r][h] = *(const short8v*)&sA[w * 32 + r * 16 + lr][h * 32 + lg * 8];
    #pragma unroll
    for (int c = 0; c < 4; ++c)
        #pragma unroll
        for (int h = 0; h < 2; ++h)
            bf2[c][h] = *(const short8v*)&sB2[c * 16 + lr][h * 32 + lg * 8];
    f32x4 acc2[2][4];
    #pragma unroll
    for (int r = 0; r < 2; ++r)
        #pragma unroll
        for (int c = 0; c < 4; ++c)
            acc2[r][c] = (f32x4){0.f, 0.f, 0.f, 0.f};
    #pragma unroll
    for (int r = 0; r < 2; ++r)
        #pragma unroll
        for (int c = 0; c < 4; ++c)
            #pragma unroll
            for (int h = 0; h < 2; ++h)
                acc2[r][c] = __builtin_amdgcn_mfma_f32_16x16x32_bf16(
                    af2[r][h], bf2[c][h], acc2[r][c], 0, 0, 0);

    // epilogue
    float c0p1 = 1.f + coeff[0];
    float bcol2[4];
    #pragma unroll
    for (int c = 0; c < 4; ++c) bcol2[c] = b2[c * 16 + lr];
    #pragma unroll
    for (int r = 0; r < 2; ++r) {
        #pragma unroll
        for (int i = 0; i < 4; ++i) {
            int row = rowBase + w * 32 + r * 16 + lg * 4 + i;
            if (row < n) {
                float dr = dinv[row];
                #pragma unroll
                for (int c = 0; c < 4; ++c) {
                    float X = acc2[r][c][i] + bcol2[c];
                    out[(size_t)row * 64 + c * 16 + lr] = c0p1 * X;
                    ty0[(size_t)row * 64 + c * 16 + lr] = bf16_rne(dr * X);
                }
            }
        }
    }
}

// ---- SpMM hop (fused out-accumulate, fp32 tx): one wave per dst row.
// 8 edge-slots x 8 feature-lanes, uint4 (16B) gathers; 4-deep chain unroll.
__global__ __launch_bounds__(256) void spmm_kernel(
    const int* __restrict__ row_ptr, const int* __restrict__ col,
    const float* __restrict__ dinv, const ushort_t* __restrict__ tyin,
    ushort_t* __restrict__ tyout, float* __restrict__ out,
    const float* __restrict__ coeff, int d, int n, int fuse_lsm) {
    int wave = (blockIdx.x * blockDim.x + threadIdx.x) >> 6;
    if (wave >= n) return;
    int lane = threadIdx.x & 63;
    int sub = lane >> 3;       // 0..7: edge slot
    int fl = lane & 7;         // feature block: feats [fl*8, fl*8+8)
    int e0 = row_ptr[wave], e1 = row_ptr[wave + 1];
    float a0 = 0.f, a1 = 0.f, a2 = 0.f, a3 = 0.f;
    float a4 = 0.f, a5 = 0.f, a6 = 0.f, a7 = 0.f;
    int e = e0 + sub;
    for (; e + 24 < e1; e += 32) {       // 4 chains in flight
        int s0 = col[e], s1 = col[e + 8], s2 = col[e + 16], s3 = col[e + 24];
        uint4 p0 = *(const uint4*)(tyin + (size_t)s0 * 64 + fl * 8);
        uint4 p1 = *(const uint4*)(tyin + (size_t)s1 * 64 + fl * 8);
        uint4 p2 = *(const uint4*)(tyin + (size_t)s2 * 64 + fl * 8);
        uint4 p3 = *(const uint4*)(tyin + (size_t)s3 * 64 + fl * 8);
        a0 += (bl(p0.x) + bl(p1.x)) + (bl(p2.x) + bl(p3.x));
        a1 += (bh(p0.x) + bh(p1.x)) + (bh(p2.x) + bh(p3.x));
        a2 += (bl(p0.y) + bl(p1.y)) + (bl(p2.y) + bl(p3.y));
        a3 += (bh(p0.y) + bh(p1.y)) + (bh(p2.y) + bh(p3.y));
        a4 += (bl(p0.z) + bl(p1.z)) + (bl(p2.z) + bl(p3.z));
        a5 += (bh(p0.z) + bh(p1.z)) + (bh(p2.z) + bh(p3.z));
        a6 += (bl(p0.w) + bl(p1.w)) + (bl(p2.w) + bl(p3.w));
        a7 += (bh(p0.w) + bh(p1.w)) + (bh(p2.w) + bh(p3.w));
    }
    for (; e + 8 < e1; e += 16) {        // 2 chains
        int s0 = col[e], s1 = col[e + 8];
        uint4 p0 = *(const uint4*)(tyin + (size_t)s0 * 64 + fl * 8);
        uint4 p1 = *(const uint4*)(tyin + (size_t)s1 * 64 + fl * 8);
        a0 += bl(p0.x) + bl(p1.x); a1 += bh(p0.x) + bh(p1.x);
        a2 += bl(p0.y) + bl(p1.y); a3 += bh(p0.y) + bh(p1.y);
        a4 += bl(p0.z) + bl(p1.z); a5 += bh(p0.z) + bh(p1.z);
        a6 += bl(p0.w) + bl(p1.w); a7 += bh(p0.w) + bh(p1.w);
    }
    if (e < e1) {
        int s = col[e];
        uint4 p = *(const uint4*)(tyin + (size_t)s * 64 + fl * 8);
        a0 += bl(p.x); a1 += bh(p.x); a2 += bl(p.y); a3 += bh(p.y);
        a4 += bl(p.z); a5 += bh(p.z); a6 += bl(p.w); a7 += bh(p.w);
    }
    #pragma unroll
    for (int off = 8; off <= 32; off <<= 1) {
        a0 += __shfl_xor(a0, off, 64); a1 += __shfl_xor(a1, off, 64);
        a2 += __shfl_xor(a2, off, 64); a3 += __shfl_xor(a3, off, 64);
        a4 += __shfl_xor(a4, off, 64); a5 += __shfl_xor(a5, off, 64);
        a6 += __shfl_xor(a6, off, 64); a7 += __shfl_xor(a7, off, 64);
    }
    float dr = dinv[wave];
    float cd = coeff[d];
    float t0 = -dr * a0, t1 = -dr * a1, t2 = -dr * a2, t3 = -dr * a3;
    float t4 = -dr * a4, t5 = -dr * a5, t6 = -dr * a6, t7 = -dr * a7;
    if (!fuse_lsm) {
        if (sub == 0) {
            float4 o0 = *(const float4*)(out + (size_t)wave * 64 + fl * 8);
            float4 o1 = *(const float4*)(out + (size_t)wave * 64 + fl * 8 + 4);
            o0.x += cd * t0; o0.y += cd * t1; o0.z += cd * t2; o0.w += cd * t3;
            o1.x += cd * t4; o1.y += cd * t5; o1.z += cd * t6; o1.w += cd * t7;
            *(float4*)(out + (size_t)wave * 64 + fl * 8) = o0;
            *(float4*)(out + (size_t)wave * 64 + fl * 8 + 4) = o1;
            uint4 ty;
            ty.x = pack_bf16x2(dr * t0, dr * t1);
            ty.y = pack_bf16x2(dr * t2, dr * t3);
            ty.z = pack_bf16x2(dr * t4, dr * t5);
            ty.w = pack_bf16x2(dr * t6, dr * t7);
            *(uint4*)(tyout + (size_t)wave * 64 + fl * 8) = ty;
        }
    } else {
        float4 o0 = *(const float4*)(out + (size_t)wave * 64 + fl * 8);
        float4 o1 = *(const float4*)(out + (size_t)wave * 64 + fl * 8 + 4);
        o0.x += cd * t0; o0.y += cd * t1; o0.z += cd * t2; o0.w += cd * t3;
        o1.x += cd * t4; o1.y += cd * t5; o1.z += cd * t6; o1.w += cd * t7;
        float m = fmaxf(fmaxf(fmaxf(o0.x, o0.y), fmaxf(o0.z, o0.w)),
                        fmaxf(fmaxf(o1.x, o1.y), fmaxf(o1.z, o1.w)));
        #pragma unroll
        for (int off = 1; off < 8; off <<= 1) m = fmaxf(m, __shfl_xor(m, off, 64));
        float se = expf(o0.x - m) + expf(o0.y - m) + expf(o0.z - m) + expf(o0.w - m)
                 + expf(o1.x - m) + expf(o1.y - m) + expf(o1.z - m) + expf(o1.w - m);
        #pragma unroll
        for (int off = 1; off < 8; off <<= 1) se += __shfl_xor(se, off, 64);
        float lse = m + logf(se);
        o0.x -= lse; o0.y -= lse; o0.z -= lse; o0.w -= lse;
        o1.x -= lse; o1.y -= lse; o1.z -= lse; o1.w -= lse;
        if (sub == 0) {
            *(float4*)(out + (size_t)wave * 64 + fl * 8) = o0;
            *(float4*)(out + (size_t)wave * 64 + fl * 8 + 4) = o1;
        }
    }
}

extern "C" void kernel_launch(void* const* d_in, const int* in_sizes, int n_in,
                              void* d_out, int out_size, void* d_ws, size_t ws_size,
                              hipStream_t stream) {
    const float* feature = (const float*)d_in[0];
    const int*   edges   = (const int*)d_in[1];
    const float* W1      = (const float*)d_in[2];
    const float* b1      = (const float*)d_in[3];
    const float* W2      = (const float*)d_in[4];
    const float* b2      = (const float*)d_in[5];
    const float* alpha   = (const float*)d_in[6];
    const float* beta    = (const float*)d_in[7];
    float* out = (float*)d_out;

    const int n = in_sizes[0] / FIN;      // 100000
    const int E = in_sizes[1] / 2;        // 3200000
    const int* src = edges;
    const int* dst = edges + E;

    const int nb = (n + 255) >> 8;        // 391 buckets of 256 nodes
    const int nchunk = (E + CHUNK - 1) / CHUNK;
    const size_t n64 = (size_t)n * 64;

    // ---- workspace layout (256B aligned) ----
    char* ws = (char*)d_ws;
    size_t off = 0;
    auto alloc = [&](size_t bytes) { size_t o = off; off = (off + bytes + 255) & ~(size_t)255; return o; };
    float*         coeff   = (float*)        (ws + alloc(64 * 4));
    float*         dinv    = (float*)        (ws + alloc((size_t)n * 4));
    int*           row_ptr = (int*)          (ws + alloc(((size_t)n + 1) * 4));
    int*           offD    = (int*)          (ws + alloc(513 * 4));
    int*           offS    = (int*)          (ws + alloc(513 * 4));
    int*           totD    = (int*)          (ws + alloc(512 * 4));
    int*           totS    = (int*)          (ws + alloc(512 * 4));
    ushort_t*      Wt      = (ushort_t*)     (ws + alloc((size_t)64 * KPAD * 2));
    ushort_t*      W2t     = (ushort_t*)     (ws + alloc((size_t)64 * 64 * 2));
    int*           histD   = (int*)          (ws + alloc((size_t)nchunk * 512 * 4));
    int*           histS   = (int*)          (ws + alloc((size_t)nchunk * 512 * 4));
    int*           col     = (int*)          (ws + alloc((size_t)E * 4));
    unsigned*      binned  = (unsigned*)     (ws + alloc((size_t)E * 4));
    unsigned char* srcbin  = (unsigned char*)(ws + alloc((size_t)E));
    ushort_t*      TyA     = (ushort_t*)     (ws + alloc(n64 * 2));
    ushort_t*      TyB     = (ushort_t*)     (ws + alloc(n64 * 2));

    // ---- host-side Taylor tables (deterministic, recomputed every call) ----
    Tables tb;
    for (int k = 0; k < KF; ++k) {
        double x = M_PI * (double)(k + 1);   // OMEGA = 1
        double p = 1.0, f = 1.0;
        for (int o = 0; o <= DORD; ++o) {
            if (o > 0) { p *= x; f *= (double)o; }
            double v = p / f;
            tb.cosc[k][o] = (o % 2 == 0) ? (float)((((o / 2) % 2 == 0) ? 1.0 : -1.0) * v) : 0.f;
            tb.sinc[k][o] = (o % 2 == 1) ? (float)(((((o - 1) / 2) % 2 == 0) ? 1.0 : -1.0) * v) : 0.f;
        }
    }

    coeff_kernel<<<1, 64, 0, stream>>>(alpha, beta, tb, coeff);
    wprep_kernel<<<(64 * KPAD + 64 * 64 + 255) / 256, 256, 0, stream>>>(W1, W2, Wt, W2t);

    hist_kernel<<<nchunk, 256, 0, stream>>>(src, dst, histD, histS, E, nb);
    scanA_kernel<<<2 * nb, 512, 0, stream>>>(histD, histS, totD, totS, nchunk, nb);
    scanB_kernel<<<1, 512, 0, stream>>>(totD, totS, offD, offS, nb);
    scatter_kernel<<<nchunk, 256, 0, stream>>>(src, dst, histD, histS, offD, offS,
                                               binned, srcbin, E, nb);
    bucket_csr_kernel<<<nb, 256, 0, stream>>>(binned, offD, row_ptr, col, n, nb);
    dinv_count_kernel<<<nb, 256, 0, stream>>>(srcbin, offS, dinv, n, nb);

    gemm12_kernel<<<(n + 127) / 128, 256, 0, stream>>>(feature, Wt, W2t, b1, b2,
                                                       coeff, dinv, TyA, out, n);

    const ushort_t* tin = TyA;
    ushort_t* bufs[2] = { TyB, TyA };
    for (int d = 1; d <= DORD; ++d) {
        ushort_t* tout = bufs[(d - 1) & 1];
        spmm_kernel<<<(n + 3) / 4, 256, 0, stream>>>(row_ptr, col, dinv, tin, tout, out,
                                                     coeff, d, n, d == DORD ? 1 : 0);
        tin = tout;
    }
}